// Round 2
// baseline (1088.192 us; speedup 1.0000x reference)
//
#include <hip/hip_runtime.h>
#include <stdint.h>
#include <stddef.h>

// ---------------------------------------------------------------------------
// JanossyPoolingImproper, round 2.
// Layer-1 factorization: U[v, j*512+c] = h[v] @ W1[j*128:(j+1)*128, c]
// (26 GF instead of 157 GF), then X1[n*3+p] = relu(b1 + sum_j U[idx[n,P[p][j]],
// j-block]) via a gather-sum (10 distinct slices/node; (i1,blk1) shared by all
// 3 perms). Then g2 (MFMA), g3 (MFMA + fused @Wo atomicAdd epilogue).
// ---------------------------------------------------------------------------

typedef __attribute__((ext_vector_type(8))) short short8;
typedef __attribute__((ext_vector_type(4))) float f32x4;
typedef __attribute__((ext_vector_type(4))) float floatv4;
typedef __attribute__((ext_vector_type(8))) unsigned short ushort8;

#define GLOAD_LDS16(g, l)                                                      \
  __builtin_amdgcn_global_load_lds(                                            \
      (const __attribute__((address_space(1))) void*)(g),                      \
      (__attribute__((address_space(3))) void*)(l), 16, 0, 0)

__device__ __forceinline__ unsigned short f2bf(float f) {
  unsigned int u = __float_as_uint(f);
  u += 0x7fffu + ((u >> 16) & 1u);  // round-to-nearest-even
  return (unsigned short)(u >> 16);
}
__device__ __forceinline__ float bf2f(unsigned short s) {
  return __uint_as_float(((unsigned int)s) << 16);
}

#define NNODES 100000
#define MTOT   300000
#define HD     512
#define NH     50000
#define NHPAD  50048   // 391 * 128
#define UW     2048

// --- Wt23[l][n][k] = bf16(W_{l+2}[k][n]), l=0,1 ------------------------------
__global__ __launch_bounds__(256) void prep_w23(const float* __restrict__ W2,
                                                const float* __restrict__ W3,
                                                unsigned short* __restrict__ Wt) {
  int t = blockIdx.x * 256 + threadIdx.x;  // < 2*512*512
  int layer = t >> 18;
  int r = t & 262143;
  int n = r >> 9, k = r & 511;
  const float* W = layer == 0 ? W2 : W3;
  Wt[t] = f2bf(W[k * 512 + n]);
}

// --- W1t[jc][k] = bf16(W1[(j*128+k)*512 + n]), jc = j*512+n ------------------
__global__ __launch_bounds__(256) void prep_w1(const float* __restrict__ W1,
                                               unsigned short* __restrict__ W1t) {
  int t = blockIdx.x * 256 + threadIdx.x;  // < 2048*128
  int jc = t >> 7, k = t & 127;
  int j = jc >> 9, n = jc & 511;
  W1t[t] = f2bf(W1[(j * 128 + k) * 512 + n]);
}

// --- hb = bf16(h), zero-padded to NHPAD rows ---------------------------------
__global__ __launch_bounds__(256) void prep_hb(const float* __restrict__ h,
                                               unsigned short* __restrict__ hb) {
  int t = blockIdx.x * 256 + threadIdx.x;  // < NHPAD*16
  int v = t >> 4, c8 = (t & 15) * 8;
  ushort8 o = {0, 0, 0, 0, 0, 0, 0, 0};
  if (v < NH) {
    const floatv4* hp = (const floatv4*)(h + (size_t)v * 128 + c8);
    floatv4 f0 = hp[0], f1 = hp[1];
#pragma unroll
    for (int e = 0; e < 4; ++e) {
      o[e] = f2bf(f0[e]);
      o[4 + e] = f2bf(f1[e]);
    }
  }
  *(ushort8*)(hb + (size_t)v * 128 + c8) = o;
}

__global__ __launch_bounds__(256) void init_out(float* __restrict__ out,
                                                const float* __restrict__ bo) {
  int t = blockIdx.x * 256 + threadIdx.x;
  if (t < 2 * NNODES) out[t] = bo[t & 1];
}

// --- prepU: U[NHPAD x 2048] = hb[NHPAD x 128] @ W1t^T, bf16 out --------------
__global__ __launch_bounds__(256) void gemm_u(const unsigned short* __restrict__ A,
                                              const unsigned short* __restrict__ Bt,
                                              unsigned short* __restrict__ U) {
  __shared__ __align__(16) char smem[34816];
  char* sA = smem;
  char* sB = smem + 16384;
  const int t = threadIdx.x;
  int bx = blockIdx.x;
  int cbk = bx & 15, rb = bx >> 4;
  int n0 = cbk * 128;
  size_t arow0 = (size_t)rb * 128;
  int w = t >> 6, l = t & 63;
  int wm = (w >> 1) * 64, wn = (w & 1) * 64;
  int m16 = l & 15, q = l >> 4;

  f32x4 acc[4][4];
#pragma unroll
  for (int i = 0; i < 4; ++i)
#pragma unroll
    for (int j = 0; j < 4; ++j) acc[i][j] = (f32x4){0.f, 0.f, 0.f, 0.f};

  for (int kt = 0; kt < 2; ++kt) {
    int kb = kt * 64;
#pragma unroll
    for (int i = 0; i < 4; ++i) {
      int s = i * 256 + t;
      int r = s >> 3;
      int cl = (s & 7) ^ (r & 7);
      GLOAD_LDS16(A + (arow0 + r) * 128 + kb + cl * 8, sA + s * 16);
    }
#pragma unroll
    for (int i = 0; i < 4; ++i) {
      int s = i * 256 + t;
      int r = s >> 3;
      int cl = (s & 7) ^ (r & 7);
      GLOAD_LDS16(Bt + (size_t)(n0 + r) * 128 + kb + cl * 8, sB + s * 16);
    }
    __syncthreads();
#pragma unroll
    for (int ks = 0; ks < 2; ++ks) {
      short8 af[4], bfr[4];
#pragma unroll
      for (int i = 0; i < 4; ++i) {
        int ra = wm + i * 16 + m16;
        int cbp = ((ks << 2) + q) ^ (m16 & 7);
        af[i] = *(const short8*)(sA + ra * 128 + cbp * 16);
        int rn = wn + i * 16 + m16;
        bfr[i] = *(const short8*)(sB + rn * 128 + cbp * 16);
      }
#pragma unroll
      for (int i = 0; i < 4; ++i)
#pragma unroll
        for (int j = 0; j < 4; ++j)
          acc[i][j] = __builtin_amdgcn_mfma_f32_16x16x32_bf16(af[i], bfr[j],
                                                              acc[i][j], 0, 0, 0);
    }
    __syncthreads();
  }
  // packed epilogue: bf16 tile -> LDS (stride 136) -> ushort8 stores
  unsigned short* L = (unsigned short*)smem;
#pragma unroll
  for (int i = 0; i < 4; ++i)
#pragma unroll
    for (int j = 0; j < 4; ++j) {
      int coll = wn + j * 16 + m16;
#pragma unroll
      for (int r = 0; r < 4; ++r) {
        int rowl = wm + i * 16 + q * 4 + r;
        L[rowl * 136 + coll] = f2bf(acc[i][j][r]);
      }
    }
  __syncthreads();
#pragma unroll
  for (int v = 0; v < 8; ++v) {
    int chunk = v * 256 + t;
    int row = chunk >> 4, ch = chunk & 15;
    ushort8 val = *(const ushort8*)(L + row * 136 + ch * 8);
    *(ushort8*)(U + (arow0 + row) * UW + n0 + ch * 8) = val;
  }
}

// --- build_x1: one wave per node, 10 U-slices -> 3 relu rows -----------------
__global__ __launch_bounds__(256) void build_x1(
    const unsigned short* __restrict__ U, const int* __restrict__ idx,
    const float* __restrict__ b1, unsigned short* __restrict__ X1, int n0c) {
  int w = threadIdx.x >> 6, l = threadIdx.x & 63;
  int nloc = blockIdx.x * 4 + w;
  int n = n0c + nloc;
  int c = l * 8;
  size_t xoff = (size_t)nloc * 3 * HD + c;
  if (n >= NNODES) {
    ushort8 z = {0, 0, 0, 0, 0, 0, 0, 0};
    *(ushort8*)(X1 + xoff) = z;
    *(ushort8*)(X1 + xoff + HD) = z;
    *(ushort8*)(X1 + xoff + 2 * HD) = z;
    return;
  }
  int i0 = idx[n * 4], i1 = idx[n * 4 + 1], i2 = idx[n * 4 + 2],
      i3 = idx[n * 4 + 3];
  const unsigned short* Ub = U + c;
  ushort8 u00 = *(const ushort8*)(Ub + (size_t)i0 * UW);
  ushort8 u20 = *(const ushort8*)(Ub + (size_t)i2 * UW);
  ushort8 u30 = *(const ushort8*)(Ub + (size_t)i3 * UW);
  ushort8 u11 = *(const ushort8*)(Ub + (size_t)i1 * UW + 512);
  ushort8 u22 = *(const ushort8*)(Ub + (size_t)i2 * UW + 1024);
  ushort8 u32 = *(const ushort8*)(Ub + (size_t)i3 * UW + 1024);
  ushort8 u02 = *(const ushort8*)(Ub + (size_t)i0 * UW + 1024);
  ushort8 u33 = *(const ushort8*)(Ub + (size_t)i3 * UW + 1536);
  ushort8 u03 = *(const ushort8*)(Ub + (size_t)i0 * UW + 1536);
  ushort8 u23 = *(const ushort8*)(Ub + (size_t)i2 * UW + 1536);
  float bv[8];
  *(floatv4*)bv = *(const floatv4*)(b1 + c);
  *(floatv4*)(bv + 4) = *(const floatv4*)(b1 + c + 4);
  ushort8 o0, o1, o2;
#pragma unroll
  for (int e = 0; e < 8; ++e) {
    float base = bf2f(u11[e]) + bv[e];
    float p0 = base + bf2f(u00[e]) + bf2f(u22[e]) + bf2f(u33[e]);
    float p1 = base + bf2f(u20[e]) + bf2f(u32[e]) + bf2f(u03[e]);
    float p2 = base + bf2f(u30[e]) + bf2f(u02[e]) + bf2f(u23[e]);
    o0[e] = f2bf(fmaxf(p0, 0.f));
    o1[e] = f2bf(fmaxf(p1, 0.f));
    o2[e] = f2bf(fmaxf(p2, 0.f));
  }
  *(ushort8*)(X1 + xoff) = o0;
  *(ushort8*)(X1 + xoff + HD) = o1;
  *(ushort8*)(X1 + xoff + 2 * HD) = o2;
}

// --- main GEMM (128x128 tile, BK=64). MODE 0: bias+relu->bf16 (packed store);
// --- MODE 1: bias+relu, fused @Wo + atomicAdd --------------------------------
template <int MODE>
__global__ __launch_bounds__(256) void gemm_mlp(
    const unsigned short* __restrict__ A, const unsigned short* __restrict__ Wt,
    const float* __restrict__ bias, unsigned short* __restrict__ Xout,
    float* __restrict__ out, const float* __restrict__ Wo, int m0glob) {
  __shared__ __align__(16) char smem[34816];
  char* sA = smem;
  char* sB = smem + 16384;
  const int t = threadIdx.x;
  int bx = blockIdx.x;
  int xcd = bx & 7, tq = bx >> 3;
  int cbk = tq & 3;
  int rb = xcd + ((tq >> 2) << 3);
  int n0 = cbk * 128;
  size_t arow0 = (size_t)rb * 128;
  int w = t >> 6, l = t & 63;
  int wm = (w >> 1) * 64, wn = (w & 1) * 64;
  int m16 = l & 15, q = l >> 4;

  f32x4 acc[4][4];
#pragma unroll
  for (int i = 0; i < 4; ++i)
#pragma unroll
    for (int j = 0; j < 4; ++j) acc[i][j] = (f32x4){0.f, 0.f, 0.f, 0.f};

  for (int kt = 0; kt < 8; ++kt) {
    int kb = kt * 64;
#pragma unroll
    for (int i = 0; i < 4; ++i) {
      int s = i * 256 + t;
      int r = s >> 3;
      int cl = (s & 7) ^ (r & 7);
      GLOAD_LDS16(A + (arow0 + r) * HD + kb + cl * 8, sA + s * 16);
    }
#pragma unroll
    for (int i = 0; i < 4; ++i) {
      int s = i * 256 + t;
      int r = s >> 3;
      int cl = (s & 7) ^ (r & 7);
      GLOAD_LDS16(Wt + (size_t)(n0 + r) * HD + kb + cl * 8, sB + s * 16);
    }
    __syncthreads();
#pragma unroll
    for (int ks = 0; ks < 2; ++ks) {
      short8 af[4], bfr[4];
#pragma unroll
      for (int i = 0; i < 4; ++i) {
        int ra = wm + i * 16 + m16;
        int cbp = ((ks << 2) + q) ^ (m16 & 7);
        af[i] = *(const short8*)(sA + ra * 128 + cbp * 16);
        int rn = wn + i * 16 + m16;
        bfr[i] = *(const short8*)(sB + rn * 128 + cbp * 16);
      }
#pragma unroll
      for (int i = 0; i < 4; ++i)
#pragma unroll
        for (int j = 0; j < 4; ++j)
          acc[i][j] = __builtin_amdgcn_mfma_f32_16x16x32_bf16(af[i], bfr[j],
                                                              acc[i][j], 0, 0, 0);
    }
    __syncthreads();
  }

  // C/D frag: col = lane&15, row = q*4 + reg
  unsigned short* L = (unsigned short*)smem;
#pragma unroll
  for (int i = 0; i < 4; ++i)
#pragma unroll
    for (int j = 0; j < 4; ++j) {
      int coll = wn + j * 16 + m16;
      float bv = bias[n0 + coll];
#pragma unroll
      for (int r = 0; r < 4; ++r) {
        int rowl = wm + i * 16 + q * 4 + r;
        float v = fmaxf(acc[i][j][r] + bv, 0.f);
        L[rowl * 136 + coll] = f2bf(v);
      }
    }
  __syncthreads();

  if (MODE == 0) {
#pragma unroll
    for (int v = 0; v < 8; ++v) {
      int chunk = v * 256 + t;
      int row = chunk >> 4, ch = chunk & 15;
      ushort8 val = *(const ushort8*)(L + row * 136 + ch * 8);
      *(ushort8*)(Xout + (arow0 + row) * HD + n0 + ch * 8) = val;
    }
  } else {
    int r2 = t >> 1, jo = t & 1;
    int grow = m0glob + rb * 128 + r2;
    if (grow < MTOT) {
      const unsigned short* Lr = L + r2 * 136;
      float s = 0.f;
#pragma unroll
      for (int cc = 0; cc < 128; cc += 2) {
        unsigned int pair = *(const unsigned int*)(Lr + cc);
        s += bf2f((unsigned short)(pair & 0xffffu)) * Wo[(n0 + cc) * 2 + jo];
        s += bf2f((unsigned short)(pair >> 16)) * Wo[(n0 + cc + 1) * 2 + jo];
      }
      int node = grow / 3;
      atomicAdd(out + node * 2 + jo, s);
    }
  }
}

extern "C" void kernel_launch(void* const* d_in, const int* in_sizes, int n_in,
                              void* d_out, int out_size, void* d_ws,
                              size_t ws_size, hipStream_t stream) {
  const float* h  = (const float*)d_in[0];
  const int*   ix = (const int*)d_in[1];
  const float* W1 = (const float*)d_in[2];
  const float* b1 = (const float*)d_in[3];
  const float* W2 = (const float*)d_in[4];
  const float* b2 = (const float*)d_in[5];
  const float* W3 = (const float*)d_in[6];
  const float* b3 = (const float*)d_in[7];
  const float* Wo = (const float*)d_in[8];
  const float* bo = (const float*)d_in[9];
  float* out = (float*)d_out;

  unsigned short* ws   = (unsigned short*)d_ws;
  unsigned short* Wt23 = ws;                        // 2*512*512      = 524288
  unsigned short* W1t  = Wt23 + 524288;             // 2048*128       = 262144
  unsigned short* hb   = W1t + 262144;              // NHPAD*128      = 6406144
  unsigned short* U    = hb + 6406144;              // NHPAD*2048     = 102498304
  unsigned short* bufs = U + 102498304;
  const size_t baseBytes = (524288ull + 262144 + 6406144 + 102498304) * 2;

  size_t avail = ws_size > baseBytes ? ws_size - baseBytes : 0;
  size_t ncap = avail / (2 * 3 * HD * sizeof(unsigned short));  // nodes (both bufs)
  size_t nc = (ncap / 1024) * 1024;
  if (nc > 100352) nc = 100352;
  if (nc == 0) nc = 1024;  // ws too small; best effort
  unsigned short* X1 = bufs;
  unsigned short* X2 = X1 + nc * 3 * HD;

  prep_w23<<<2048, 256, 0, stream>>>(W2, W3, Wt23);
  prep_w1<<<1024, 256, 0, stream>>>(W1, W1t);
  prep_hb<<<NHPAD * 16 / 256, 256, 0, stream>>>(h, hb);
  init_out<<<(2 * NNODES + 255) / 256, 256, 0, stream>>>(out, bo);
  gemm_u<<<391 * 16, 256, 0, stream>>>(hb, W1t, U);

  for (size_t n0c = 0; n0c < NNODES; n0c += nc) {
    size_t remn = (size_t)NNODES - n0c;
    size_t ncp = remn < nc ? ((remn + 1023) / 1024) * 1024 : nc;
    int rows = (int)(ncp * 3);    // multiple of 3072 -> RB divisible by 8
    int RB = rows / 128;
    build_x1<<<(int)(ncp / 4), 256, 0, stream>>>(U, ix, b1, X1, (int)n0c);
    gemm_mlp<0><<<RB * 4, 256, 0, stream>>>(X1, Wt23, b2, X2, nullptr, nullptr, 0);
    gemm_mlp<1><<<RB * 4, 256, 0, stream>>>(X2, Wt23 + 262144, b3, nullptr, out,
                                            Wo, (int)(3 * n0c));
  }
}

// Round 3
// 758.991 us; speedup vs baseline: 1.4337x; 1.4337x over previous
//
#include <hip/hip_runtime.h>
#include <stdint.h>
#include <stddef.h>

// ---------------------------------------------------------------------------
// Round 3: back to 3 chained GEMMs, but (a) gather fused into GEMM-1's
// A-staging (reads L3-resident bf16 hb via idx table in LDS; X0 never
// materialized), (b) BM=256 tiles to amortize per-block overhead over 2x
// FLOPs (K=512 -> only 8 K-tiles; prologue/epilogue was ~40% of block time),
// (c) GEMM-3 fuses @Wo + atomicAdd epilogue.
// ---------------------------------------------------------------------------

typedef __attribute__((ext_vector_type(8))) short short8;
typedef __attribute__((ext_vector_type(4))) float f32x4;
typedef __attribute__((ext_vector_type(4))) float floatv4;
typedef __attribute__((ext_vector_type(8))) unsigned short ushort8;

#define GLOAD_LDS16(g, l)                                                      \
  __builtin_amdgcn_global_load_lds(                                            \
      (const __attribute__((address_space(1))) void*)(g),                      \
      (__attribute__((address_space(3))) void*)(l), 16, 0, 0)

__device__ __forceinline__ unsigned short f2bf(float f) {
  unsigned int u = __float_as_uint(f);
  u += 0x7fffu + ((u >> 16) & 1u);  // RNE
  return (unsigned short)(u >> 16);
}
__device__ __forceinline__ float bf2f(unsigned short s) {
  return __uint_as_float(((unsigned int)s) << 16);
}

#define NNODES 100000
#define MTOT   300000
#define HD     512
#define NH     50000

// --- Wt[layer][n][k] = bf16(W[k][n]) ----------------------------------------
__global__ __launch_bounds__(256) void prep_w(const float* __restrict__ W1,
                                              const float* __restrict__ W2,
                                              const float* __restrict__ W3,
                                              unsigned short* __restrict__ Wt) {
  int t = blockIdx.x * 256 + threadIdx.x;  // < 3*512*512
  int layer = t >> 18;
  int r = t & 262143;
  int n = r >> 9, k = r & 511;
  const float* W = layer == 0 ? W1 : (layer == 1 ? W2 : W3);
  Wt[t] = f2bf(W[k * 512 + n]);
}

// --- hb = bf16(h) [50000 x 128] ---------------------------------------------
__global__ __launch_bounds__(256) void prep_hb(const float* __restrict__ h,
                                               unsigned short* __restrict__ hb) {
  int t = blockIdx.x * 256 + threadIdx.x;  // < NH*16
  int v = t >> 4, c8 = (t & 15) * 8;
  const floatv4* hp = (const floatv4*)(h + (size_t)v * 128 + c8);
  floatv4 f0 = hp[0], f1 = hp[1];
  ushort8 o;
#pragma unroll
  for (int e = 0; e < 4; ++e) {
    o[e] = f2bf(f0[e]);
    o[4 + e] = f2bf(f1[e]);
  }
  *(ushort8*)(hb + (size_t)v * 128 + c8) = o;
}

__global__ __launch_bounds__(256) void init_out(float* __restrict__ out,
                                                const float* __restrict__ bo) {
  int t = blockIdx.x * 256 + threadIdx.x;
  if (t < 2 * NNODES) out[t] = bo[t & 1];
}

// --- GEMM: 256x128 tile, BK=64, K=512. GATHER: A staged from hb via idx.
// --- FINAL: fused @Wo + atomicAdd. Else: bias+relu -> bf16 X (packed). ------
template <int GATHER, int FINAL>
__global__ __launch_bounds__(256, 2) void gemm_k(
    const unsigned short* __restrict__ A,   // GATHER ? hb : X-in (row-major 512)
    const int* __restrict__ idx,
    const unsigned short* __restrict__ Wt,
    const float* __restrict__ bias,
    unsigned short* __restrict__ Xout,
    float* __restrict__ out, const float* __restrict__ Wo,
    int mchunk0) {                          // global row base of this chunk
  __shared__ __align__(16) char smem[53248];
  char* sA = smem;                    // 256 rows x 128 B = 32768
  char* sB = smem + 32768;            // 128 rows x 128 B = 16384
  int* sIdx = (int*)(smem + 49152);   // 256 rows x 4 ints = 4096

  const int t = threadIdx.x;
  int bx = blockIdx.x;
  // XCD swizzle: 4 col-blocks of one row-block land on one XCD.
  int xcd = bx & 7, tq = bx >> 3;
  int cbk = tq & 3;
  int rb = xcd + ((tq >> 2) << 3);
  int n0 = cbk * 128;
  int arow0 = rb * 256;               // chunk-local row base
  int w = t >> 6, l = t & 63;
  int m16 = l & 15, q = l >> 4;

  if (GATHER) {
    // per-row neighbor table: sIdx[r*4+j] = idx[n*4 + PERM[p][j]]
    int m = mchunk0 + arow0 + t;
    unsigned um = (unsigned)m;
    unsigned n = um / 3u;
    int p = (int)(um - n * 3u);
    if (n >= NNODES) n = 0;  // padded tail rows: junk, guarded at output
    const unsigned pk0 = 0x320u, pk1 = 0x111u, pk2 = 0x032u, pk3 = 0x203u;
    int sh = p * 4;
    sIdx[t * 4 + 0] = idx[n * 4 + ((pk0 >> sh) & 0xFu)];
    sIdx[t * 4 + 1] = idx[n * 4 + ((pk1 >> sh) & 0xFu)];
    sIdx[t * 4 + 2] = idx[n * 4 + ((pk2 >> sh) & 0xFu)];
    sIdx[t * 4 + 3] = idx[n * 4 + ((pk3 >> sh) & 0xFu)];
    __syncthreads();
  }

  f32x4 acc[4][8];
#pragma unroll
  for (int i = 0; i < 4; ++i)
#pragma unroll
    for (int j = 0; j < 8; ++j) acc[i][j] = (f32x4){0.f, 0.f, 0.f, 0.f};

  for (int kt = 0; kt < 8; ++kt) {
    int kb = kt * 64;
    if (GATHER) {
      int jblk = kt >> 1;
      int inner = (kt & 1) * 64;
#pragma unroll
      for (int i = 0; i < 8; ++i) {
        int s = i * 256 + t;
        int r = s >> 3;
        int cl = (s & 7) ^ (r & 7);
        int src = sIdx[r * 4 + jblk];
        GLOAD_LDS16(A + (size_t)src * 128 + inner + cl * 8, sA + s * 16);
      }
    } else {
#pragma unroll
      for (int i = 0; i < 8; ++i) {
        int s = i * 256 + t;
        int r = s >> 3;
        int cl = (s & 7) ^ (r & 7);
        GLOAD_LDS16(A + (size_t)(arow0 + r) * HD + kb + cl * 8, sA + s * 16);
      }
    }
#pragma unroll
    for (int i = 0; i < 4; ++i) {
      int s = i * 256 + t;
      int r = s >> 3;
      int cl = (s & 7) ^ (r & 7);
      GLOAD_LDS16(Wt + (size_t)(n0 + r) * HD + kb + cl * 8, sB + s * 16);
    }
    __syncthreads();
#pragma unroll
    for (int ks = 0; ks < 2; ++ks) {
      short8 af[4], bfr[8];
      int cbp = ((ks << 2) + q) ^ (m16 & 7);
#pragma unroll
      for (int i = 0; i < 4; ++i) {
        int ra = w * 64 + i * 16 + m16;
        af[i] = *(const short8*)(sA + ra * 128 + cbp * 16);
      }
#pragma unroll
      for (int j = 0; j < 8; ++j) {
        int rn = j * 16 + m16;
        bfr[j] = *(const short8*)(sB + rn * 128 + cbp * 16);
      }
#pragma unroll
      for (int i = 0; i < 4; ++i)
#pragma unroll
        for (int j = 0; j < 8; ++j)
          acc[i][j] = __builtin_amdgcn_mfma_f32_16x16x32_bf16(af[i], bfr[j],
                                                              acc[i][j], 0, 0, 0);
    }
    __syncthreads();
  }

  // Epilogue in 2 phases of 128 rows (L = 128 x 136 shorts fits smem).
  // C/D frag: col = lane&15, row = q*4 + reg.
  unsigned short* L = (unsigned short*)smem;
  for (int ph = 0; ph < 2; ++ph) {
    __syncthreads();
    if ((w >> 1) == ph) {
      int wl = w & 1;
#pragma unroll
      for (int i = 0; i < 4; ++i)
#pragma unroll
        for (int j = 0; j < 8; ++j) {
          int coll = j * 16 + m16;
          float bv = bias[n0 + coll];
#pragma unroll
          for (int r = 0; r < 4; ++r) {
            int rowl = wl * 64 + i * 16 + q * 4 + r;
            float v = fmaxf(acc[i][j][r] + bv, 0.f);
            L[rowl * 136 + coll] = f2bf(v);
          }
        }
    }
    __syncthreads();
    if (!FINAL) {
#pragma unroll
      for (int v = 0; v < 8; ++v) {
        int chunk = v * 256 + t;
        int row = chunk >> 4, ch = chunk & 15;
        ushort8 val = *(const ushort8*)(L + row * 136 + ch * 8);
        *(ushort8*)(Xout + (size_t)(arow0 + ph * 128 + row) * HD + n0 + ch * 8) =
            val;
      }
    } else {
      int r2 = t >> 1, jo = t & 1;
      int grow = mchunk0 + arow0 + ph * 128 + r2;
      if (grow < MTOT) {
        const unsigned short* Lr = L + r2 * 136;
        float s = 0.f;
#pragma unroll
        for (int cc = 0; cc < 128; cc += 2) {
          unsigned int pair = *(const unsigned int*)(Lr + cc);
          s += bf2f((unsigned short)(pair & 0xffffu)) * Wo[(n0 + cc) * 2 + jo];
          s += bf2f((unsigned short)(pair >> 16)) * Wo[(n0 + cc + 1) * 2 + jo];
        }
        int node = grow / 3;
        atomicAdd(out + node * 2 + jo, s);
      }
    }
  }
}

extern "C" void kernel_launch(void* const* d_in, const int* in_sizes, int n_in,
                              void* d_out, int out_size, void* d_ws,
                              size_t ws_size, hipStream_t stream) {
  const float* h  = (const float*)d_in[0];
  const int*   ix = (const int*)d_in[1];
  const float* W1 = (const float*)d_in[2];
  const float* b1 = (const float*)d_in[3];
  const float* W2 = (const float*)d_in[4];
  const float* b2 = (const float*)d_in[5];
  const float* W3 = (const float*)d_in[6];
  const float* b3 = (const float*)d_in[7];
  const float* Wo = (const float*)d_in[8];
  const float* bo = (const float*)d_in[9];
  float* out = (float*)d_out;

  unsigned short* ws = (unsigned short*)d_ws;
  unsigned short* Wt = ws;                  // 3*512*512 shorts
  unsigned short* hb = Wt + 786432;         // 50000*128 shorts
  unsigned short* bufs = hb + 6400000;
  const size_t baseBytes = (786432ull + 6400000ull) * 2;

  // nodes per chunk: multiple of 2048 so rows%256==0 and RB%8==0
  size_t avail = ws_size > baseBytes ? ws_size - baseBytes : 0;
  size_t ncap = avail / (2ull * 3 * HD * sizeof(unsigned short));
  size_t nc = (ncap / 2048) * 2048;
  if (nc > 32768) nc = 32768;
  if (nc == 0) nc = 2048;  // best effort
  unsigned short* X1 = bufs;
  unsigned short* X2 = X1 + nc * 3 * HD;

  prep_w<<<3072, 256, 0, stream>>>(W1, W2, W3, Wt);
  prep_hb<<<NH * 16 / 256, 256, 0, stream>>>(h, hb);
  init_out<<<(2 * NNODES + 255) / 256, 256, 0, stream>>>(out, bo);

  for (size_t n0c = 0; n0c < NNODES; n0c += nc) {
    size_t remn = (size_t)NNODES - n0c;
    size_t ncp = remn < nc ? ((remn + 2047) / 2048) * 2048 : nc;
    int rows = (int)(ncp * 3);
    int RB = rows / 256;
    int m0 = (int)(3 * n0c);
    gemm_k<1, 0><<<RB * 4, 256, 0, stream>>>(hb, ix, Wt, b1, X1, nullptr,
                                             nullptr, m0);
    gemm_k<0, 0><<<RB * 4, 256, 0, stream>>>(X1, nullptr, Wt + 262144, b2, X2,
                                             nullptr, nullptr, m0);
    gemm_k<0, 1><<<RB * 4, 256, 0, stream>>>(X2, nullptr, Wt + 524288, b3,
                                             nullptr, out, Wo, m0);
  }
}

// Round 4
// 700.941 us; speedup vs baseline: 1.5525x; 1.0828x over previous
//
#include <hip/hip_runtime.h>
#include <stdint.h>
#include <stddef.h>

// ---------------------------------------------------------------------------
// Round 4: 3 chained GEMMs, gather fused into GEMM-1 A-staging.
// Change vs round 3: BM=128 tile with 32x32x16 MFMA (wave tile 64x64 as 2x2
// frags of 32x32), acc = 64 AGPR; __launch_bounds__(256,4) targets 128
// regs/wave -> 4 blocks/CU (round-3's acc[4][8]=128 AGPR + 112 VGPR capped
// occupancy at 2 blocks/CU and MfmaUtil at 26%). Fewer MFMA instructions
// (16/kt vs 32/kt) at 2x FLOP each; 32x32 shape ubenches 15% faster.
// ---------------------------------------------------------------------------

typedef __attribute__((ext_vector_type(8))) short short8;
typedef __attribute__((ext_vector_type(16))) float f32x16;
typedef __attribute__((ext_vector_type(4))) float floatv4;
typedef __attribute__((ext_vector_type(8))) unsigned short ushort8;

#define GLOAD_LDS16(g, l)                                                      \
  __builtin_amdgcn_global_load_lds(                                            \
      (const __attribute__((address_space(1))) void*)(g),                      \
      (__attribute__((address_space(3))) void*)(l), 16, 0, 0)

__device__ __forceinline__ unsigned short f2bf(float f) {
  unsigned int u = __float_as_uint(f);
  u += 0x7fffu + ((u >> 16) & 1u);  // RNE
  return (unsigned short)(u >> 16);
}
__device__ __forceinline__ float bf2f(unsigned short s) {
  return __uint_as_float(((unsigned int)s) << 16);
}

#define NNODES 100000
#define MTOT   300000
#define HD     512
#define NH     50000

// --- Wt[layer][n][k] = bf16(W[k][n]) ----------------------------------------
__global__ __launch_bounds__(256) void prep_w(const float* __restrict__ W1,
                                              const float* __restrict__ W2,
                                              const float* __restrict__ W3,
                                              unsigned short* __restrict__ Wt) {
  int t = blockIdx.x * 256 + threadIdx.x;  // < 3*512*512
  int layer = t >> 18;
  int r = t & 262143;
  int n = r >> 9, k = r & 511;
  const float* W = layer == 0 ? W1 : (layer == 1 ? W2 : W3);
  Wt[t] = f2bf(W[k * 512 + n]);
}

// --- hb = bf16(h) [50000 x 128] ---------------------------------------------
__global__ __launch_bounds__(256) void prep_hb(const float* __restrict__ h,
                                               unsigned short* __restrict__ hb) {
  int t = blockIdx.x * 256 + threadIdx.x;  // < NH*16
  int v = t >> 4, c8 = (t & 15) * 8;
  const floatv4* hp = (const floatv4*)(h + (size_t)v * 128 + c8);
  floatv4 f0 = hp[0], f1 = hp[1];
  ushort8 o;
#pragma unroll
  for (int e = 0; e < 4; ++e) {
    o[e] = f2bf(f0[e]);
    o[4 + e] = f2bf(f1[e]);
  }
  *(ushort8*)(hb + (size_t)v * 128 + c8) = o;
}

__global__ __launch_bounds__(256) void init_out(float* __restrict__ out,
                                                const float* __restrict__ bo) {
  int t = blockIdx.x * 256 + threadIdx.x;
  if (t < 2 * NNODES) out[t] = bo[t & 1];
}

// --- GEMM: 128x128 tile, BK=64, K=512, 32x32x16 MFMA. ------------------------
// GATHER: A staged from hb via idx table. FINAL: fused @Wo + atomicAdd.
template <int GATHER, int FINAL>
__global__ __launch_bounds__(256, 4) void gemm_k(
    const unsigned short* __restrict__ A,   // GATHER ? hb : X-in (row-major 512)
    const int* __restrict__ idx,
    const unsigned short* __restrict__ Wt,
    const float* __restrict__ bias,
    unsigned short* __restrict__ Xout,
    float* __restrict__ out, const float* __restrict__ Wo,
    int mchunk0) {
  __shared__ __align__(16) char smem[36864];
  char* sA = smem;                    // 128 rows x 128 B = 16384
  char* sB = smem + 16384;            // 128 rows x 128 B = 16384
  int* sIdx = (int*)(smem + 32768);   // 128 rows x 4 ints = 2048

  const int t = threadIdx.x;
  int bx = blockIdx.x;
  // XCD swizzle: 4 col-blocks of one row-block land on one XCD.
  int xcd = bx & 7, tq = bx >> 3;
  int cbk = tq & 3;
  int rb = xcd + ((tq >> 2) << 3);
  int n0 = cbk * 128;
  int arow0 = rb * 128;               // chunk-local row base
  int w = t >> 6, l = t & 63;
  int wm = (w >> 1) * 64, wn = (w & 1) * 64;
  int m32 = l & 31, half = l >> 5;

  if (GATHER) {
    if (t < 128) {
      int m = mchunk0 + arow0 + t;
      unsigned um = (unsigned)m;
      unsigned n = um / 3u;
      int p = (int)(um - n * 3u);
      if (n >= NNODES) n = 0;  // padded tail rows: junk, guarded at output
      const unsigned pk0 = 0x320u, pk1 = 0x111u, pk2 = 0x032u, pk3 = 0x203u;
      int sh = p * 4;
      sIdx[t * 4 + 0] = idx[n * 4 + ((pk0 >> sh) & 0xFu)];
      sIdx[t * 4 + 1] = idx[n * 4 + ((pk1 >> sh) & 0xFu)];
      sIdx[t * 4 + 2] = idx[n * 4 + ((pk2 >> sh) & 0xFu)];
      sIdx[t * 4 + 3] = idx[n * 4 + ((pk3 >> sh) & 0xFu)];
    }
    __syncthreads();
  }

  f32x16 acc[2][2];
#pragma unroll
  for (int i = 0; i < 2; ++i)
#pragma unroll
    for (int j = 0; j < 2; ++j)
#pragma unroll
      for (int r = 0; r < 16; ++r) acc[i][j][r] = 0.f;

  for (int kt = 0; kt < 8; ++kt) {
    int kb = kt * 64;
    if (GATHER) {
      int jblk = kt >> 1;
      int inner = (kt & 1) * 64;
#pragma unroll
      for (int i = 0; i < 4; ++i) {
        int s = i * 256 + t;
        int r = s >> 3;
        int cl = (s & 7) ^ (r & 7);
        int src = sIdx[r * 4 + jblk];
        GLOAD_LDS16(A + (size_t)src * 128 + inner + cl * 8, sA + s * 16);
      }
    } else {
#pragma unroll
      for (int i = 0; i < 4; ++i) {
        int s = i * 256 + t;
        int r = s >> 3;
        int cl = (s & 7) ^ (r & 7);
        GLOAD_LDS16(A + (size_t)(arow0 + r) * HD + kb + cl * 8, sA + s * 16);
      }
    }
#pragma unroll
    for (int i = 0; i < 4; ++i) {
      int s = i * 256 + t;
      int r = s >> 3;
      int cl = (s & 7) ^ (r & 7);
      GLOAD_LDS16(Wt + (size_t)(n0 + r) * HD + kb + cl * 8, sB + s * 16);
    }
    __syncthreads();
    // A frag (32x32x16): m = lane&31, k = (lane>>5)*8 + j; B mirrors on n.
#pragma unroll
    for (int ks = 0; ks < 4; ++ks) {
      short8 af[2], bfr[2];
      int cb = ((ks << 1) + half) ^ (m32 & 7);  // 16B-block col, XOR-swizzled
#pragma unroll
      for (int i = 0; i < 2; ++i)
        af[i] = *(const short8*)(sA + (wm + i * 32 + m32) * 128 + cb * 16);
#pragma unroll
      for (int j = 0; j < 2; ++j)
        bfr[j] = *(const short8*)(sB + (wn + j * 32 + m32) * 128 + cb * 16);
#pragma unroll
      for (int i = 0; i < 2; ++i)
#pragma unroll
        for (int j = 0; j < 2; ++j)
          acc[i][j] = __builtin_amdgcn_mfma_f32_32x32x16_bf16(af[i], bfr[j],
                                                              acc[i][j], 0, 0, 0);
    }
    __syncthreads();
  }

  // Epilogue. 32x32 C/D: col = lane&31, row = (reg&3) + 8*(reg>>2) + 4*half.
  unsigned short* L = (unsigned short*)smem;
#pragma unroll
  for (int i = 0; i < 2; ++i)
#pragma unroll
    for (int j = 0; j < 2; ++j) {
      int coll = wn + j * 32 + m32;
      float bv = bias[n0 + coll];
#pragma unroll
      for (int r = 0; r < 16; ++r) {
        int rowl = wm + i * 32 + (r & 3) + 8 * (r >> 2) + 4 * half;
        float v = fmaxf(acc[i][j][r] + bv, 0.f);
        L[rowl * 136 + coll] = f2bf(v);
      }
    }
  __syncthreads();

  if (!FINAL) {
#pragma unroll
    for (int v = 0; v < 8; ++v) {
      int chunk = v * 256 + t;
      int row = chunk >> 4, ch = chunk & 15;
      ushort8 val = *(const ushort8*)(L + row * 136 + ch * 8);
      *(ushort8*)(Xout + (size_t)(arow0 + row) * HD + n0 + ch * 8) = val;
    }
  } else {
    int r2 = t >> 1, jo = t & 1;
    int grow = mchunk0 + arow0 + r2;
    if (grow < MTOT) {
      const unsigned short* Lr = L + r2 * 136;
      float s = 0.f;
#pragma unroll
      for (int cc = 0; cc < 128; cc += 2) {
        unsigned int pair = *(const unsigned int*)(Lr + cc);
        s += bf2f((unsigned short)(pair & 0xffffu)) * Wo[(n0 + cc) * 2 + jo];
        s += bf2f((unsigned short)(pair >> 16)) * Wo[(n0 + cc + 1) * 2 + jo];
      }
      int node = grow / 3;
      atomicAdd(out + node * 2 + jo, s);
    }
  }
}

extern "C" void kernel_launch(void* const* d_in, const int* in_sizes, int n_in,
                              void* d_out, int out_size, void* d_ws,
                              size_t ws_size, hipStream_t stream) {
  const float* h  = (const float*)d_in[0];
  const int*   ix = (const int*)d_in[1];
  const float* W1 = (const float*)d_in[2];
  const float* b1 = (const float*)d_in[3];
  const float* W2 = (const float*)d_in[4];
  const float* b2 = (const float*)d_in[5];
  const float* W3 = (const float*)d_in[6];
  const float* b3 = (const float*)d_in[7];
  const float* Wo = (const float*)d_in[8];
  const float* bo = (const float*)d_in[9];
  float* out = (float*)d_out;

  unsigned short* ws = (unsigned short*)d_ws;
  unsigned short* Wt = ws;                  // 3*512*512 shorts
  unsigned short* hb = Wt + 786432;         // 50000*128 shorts
  unsigned short* bufs = hb + 6400000;
  const size_t baseBytes = (786432ull + 6400000ull) * 2;

  // nodes per chunk: multiple of 2048 so rows%1024==0 -> RB%8==0
  size_t avail = ws_size > baseBytes ? ws_size - baseBytes : 0;
  size_t ncap = avail / (2ull * 3 * HD * sizeof(unsigned short));
  size_t nc = (ncap / 2048) * 2048;
  if (nc > 32768) nc = 32768;
  if (nc == 0) nc = 2048;  // best effort
  unsigned short* X1 = bufs;
  unsigned short* X2 = X1 + nc * 3 * HD;

  prep_w<<<3072, 256, 0, stream>>>(W1, W2, W3, Wt);
  prep_hb<<<NH * 16 / 256, 256, 0, stream>>>(h, hb);
  init_out<<<(2 * NNODES + 255) / 256, 256, 0, stream>>>(out, bo);

  for (size_t n0c = 0; n0c < NNODES; n0c += nc) {
    size_t remn = (size_t)NNODES - n0c;
    size_t ncp = remn < nc ? ((remn + 2047) / 2048) * 2048 : nc;
    int rows = (int)(ncp * 3);
    int RB = rows / 128;
    int m0 = (int)(3 * n0c);
    gemm_k<1, 0><<<RB * 4, 256, 0, stream>>>(hb, ix, Wt, b1, X1, nullptr,
                                             nullptr, m0);
    gemm_k<0, 0><<<RB * 4, 256, 0, stream>>>(X1, nullptr, Wt + 262144, b2, X2,
                                             nullptr, nullptr, m0);
    gemm_k<0, 1><<<RB * 4, 256, 0, stream>>>(X2, nullptr, Wt + 524288, b3,
                                             nullptr, out, Wo, m0);
  }
}